// Round 11
// baseline (2325.369 us; speedup 1.0000x reference)
//
#include <hip/hip_runtime.h>
#include <hip/hip_bf16.h>
#include <math.h>

#define NA 50000
#define NS 5000
#define E_AA 500000
#define E_AS 250000
#define CDIM 128
#define ED 8
#define NAPAD 50176   // 196*256
#define NSPAD 5120    // 20*256
#define SCAN_CH 2048  // elements per scan block (256 thr x 8)
#define AGG_BLOCKS 1024
#define AGG_BLK_AA 711   // R6-proven split: AA 500k/711, AS 250k/313

typedef __attribute__((ext_vector_type(8))) short bf16x8;
typedef __attribute__((ext_vector_type(4))) float f32x4;

__device__ inline short f2bf(float f) {
    __hip_bfloat16 h = __float2bfloat16(f);
    return *(short*)&h;
}
__device__ inline float bf2f(short s) {
    union { unsigned int u; float f; } cv;
    cv.u = ((unsigned int)(unsigned short)s) << 16;
    return cv.f;
}

// ---------------- small helpers ----------------

__device__ inline float4 f4fma(float s, float4 a, float4 b) {
    return make_float4(fmaf(s, a.x, b.x), fmaf(s, a.y, b.y),
                       fmaf(s, a.z, b.z), fmaf(s, a.w, b.w));
}
__device__ inline float4 f4add(float4 a, float4 b) {
    return make_float4(a.x + b.x, a.y + b.y, a.z + b.z, a.w + b.w);
}
__device__ inline float4 f4leaky(float4 a) {
    return make_float4(a.x > 0.f ? a.x : 0.2f * a.x, a.y > 0.f ? a.y : 0.2f * a.y,
                       a.z > 0.f ? a.z : 0.2f * a.z, a.w > 0.f ? a.w : 0.2f * a.w);
}
__device__ inline float f4dot(float4 a, float4 b) {
    return a.x * b.x + a.y * b.y + a.z * b.z + a.w * b.w;
}
__device__ inline float4 f4mix(float sc, float4 a, float p, float4 x) {
    return make_float4(fmaf(sc, a.x, p * x.x), fmaf(sc, a.y, p * x.y),
                       fmaf(sc, a.z, p * x.z), fmaf(sc, a.w, p * x.w));
}
__device__ inline float4 bfh2f4(bf16x8 v, int half) {
    int o = half * 4;
    return make_float4(bf2f(v[o]), bf2f(v[o + 1]), bf2f(v[o + 2]), bf2f(v[o + 3]));
}

// ---------------- fused prep: count degrees + cvt inputs + weight transpose (R12) ----

__global__ __launch_bounds__(256) void prep1_k(
    const int* __restrict__ dst0, const int* __restrict__ dst1,
    int* __restrict__ deg0, int* __restrict__ deg1,
    const float* __restrict__ xa, const float* __restrict__ xs,
    short* __restrict__ Xb, short* __restrict__ Xsb,
    const float* __restrict__ Wl0_aa, const float* __restrict__ Wr0_aa,
    const float* __restrict__ Wl0_as, const float* __restrict__ Wr0_as,
    const float* __restrict__ Wl_aa, const float* __restrict__ Wr_aa,
    const float* __restrict__ Wl_as, const float* __restrict__ Wr_as,
    short* __restrict__ Wt, int gCnt, int gCvt) {
    int b = blockIdx.x;
    if (b < gCnt) {
        int e = b * 256 + threadIdx.x;
        if (e < E_AA) atomicAdd(&deg0[dst0[e]], 1);
        if (e < E_AS) atomicAdd(&deg1[dst1[e]], 1);
        return;
    }
    b -= gCnt;
    if (b < gCvt) {
        const int t4A = NAPAD * 32;
        const int t4S = NSPAD * 32;
        int i = b * 256 + threadIdx.x;
        if (i < t4A) {
            int row = i >> 5, c4 = i & 31;
            float4 v = make_float4(0.f, 0.f, 0.f, 0.f);
            if (row < NA) v = ((const float4*)xa)[(size_t)row * 32 + c4];
            short4 s;
            s.x = f2bf(v.x); s.y = f2bf(v.y); s.z = f2bf(v.z); s.w = f2bf(v.w);
            ((short4*)Xb)[i] = s;
        } else if (i < t4A + t4S) {
            int j = i - t4A;
            int row = j >> 5, c4 = j & 31;
            float4 v = make_float4(0.f, 0.f, 0.f, 0.f);
            if (row < NS && c4 < 16) v = ((const float4*)xs)[(size_t)row * 16 + c4];
            short4 s;
            s.x = f2bf(v.x); s.y = f2bf(v.y); s.z = f2bf(v.z); s.w = f2bf(v.w);
            ((short4*)Xsb)[j] = s;
        }
        return;
    }
    b -= gCvt;
    {
        int mat = b >> 6;            // 0..11
        int layer = mat >> 2, w = mat & 3;
        int idx = (b & 63) * 256 + threadIdx.x;  // k*128+n
        int k = idx >> 7, n = idx & 127;
        const float* W;
        int K = 128;
        if (layer == 0) {
            W = (w == 0) ? Wl0_aa : (w == 1) ? Wr0_aa : (w == 2) ? Wl0_as : Wr0_as;
            if (w == 3) K = 64;
        } else {
            int j = layer - 1;
            W = ((w == 0) ? Wl_aa : (w == 1) ? Wr_aa : (w == 2) ? Wl_as : Wr_as)
                + (size_t)j * 16384;
        }
        float v = (k < K) ? W[(size_t)k * 128 + n] : 0.f;
        Wt[(size_t)mat * 16384 + n * 128 + k] = f2bf(v);
    }
}

// phase A: per-block sums of deg (two concatenated arrays)
__global__ __launch_bounds__(256) void scanA_k(const int* __restrict__ deg0, int n0,
                                               const int* __restrict__ deg1, int n1,
                                               int nb0, int* __restrict__ bsum) {
    int b = blockIdx.x;
    const int* deg; int n; int lb;
    if ((int)b < nb0) { deg = deg0; n = n0; lb = b; }
    else { deg = deg1; n = n1; lb = b - nb0; }
    int t = threadIdx.x;
    int base = lb * SCAN_CH + t * 8;
    int s = 0;
    #pragma unroll
    for (int i = 0; i < 8; ++i) { int idx = base + i; s += (idx < n) ? deg[idx] : 0; }
    int lane = t & 63, w = t >> 6;
    #pragma unroll
    for (int off = 1; off < 64; off <<= 1) {
        int u = __shfl_up(s, off, 64);
        if (lane >= off) s += u;
    }
    __shared__ int ws[4];
    if (lane == 63) ws[w] = s;
    __syncthreads();
    if (t == 0) bsum[blockIdx.x] = ws[0] + ws[1] + ws[2] + ws[3];
}

// phase B: exclusive-scan the block sums (two segments) in one wave
__global__ void scanB_k(int* __restrict__ bsum, int nb0, int nb1) {
    int t = threadIdx.x;   // 64
    int n = nb0 + nb1;
    int v = (t < n) ? bsum[t] : 0;
    int incl = v;
    #pragma unroll
    for (int off = 1; off < 64; off <<= 1) {
        int u = __shfl_up(incl, off, 64);
        if (t >= off) incl += u;
    }
    int excl = incl - v;
    int sum0 = __shfl(incl, nb0 - 1, 64);
    if (t >= nb0) excl -= sum0;
    if (t < n) bsum[t] = excl;
}

// phase C: block-local prefix + global offset -> row_start (exclusive), plus rs[n]
__global__ __launch_bounds__(256) void scanC_k(const int* __restrict__ deg0, int n0,
                                               const int* __restrict__ deg1, int n1,
                                               int nb0, const int* __restrict__ bsum,
                                               int* __restrict__ rs0, int* __restrict__ rs1) {
    int b = blockIdx.x;
    const int* deg; int n; int* rs; int lb;
    if ((int)b < nb0) { deg = deg0; n = n0; rs = rs0; lb = b; }
    else { deg = deg1; n = n1; rs = rs1; lb = b - nb0; }
    int boff = bsum[b];
    int t = threadIdx.x;
    int base = lb * SCAN_CH + t * 8;
    int v[8];
    int tsum = 0;
    #pragma unroll
    for (int i = 0; i < 8; ++i) {
        int idx = base + i;
        v[i] = (idx < n) ? deg[idx] : 0;
        tsum += v[i];
    }
    int lane = t & 63, w = t >> 6;
    int incl = tsum;
    #pragma unroll
    for (int off = 1; off < 64; off <<= 1) {
        int u = __shfl_up(incl, off, 64);
        if (lane >= off) incl += u;
    }
    __shared__ int ws[4];
    if (lane == 63) ws[w] = incl;
    __syncthreads();
    int woff = 0;
    for (int i = 0; i < w; ++i) woff += ws[i];
    int run = boff + woff + incl - tsum;
    #pragma unroll
    for (int i = 0; i < 8; ++i) {
        int idx = base + i;
        if (idx < n) {
            rs[idx] = run;
            run += v[i];
            if (idx == n - 1) rs[n] = run;
        }
    }
}

// scatter: build csr_src + CSR-ordered bf16 edge attrs (kills 1 gather hop in agg)
__global__ __launch_bounds__(256) void scatter2_k(
    const int* __restrict__ dst0, const int* __restrict__ src0, const float* __restrict__ ea0,
    const int* __restrict__ dst1, const int* __restrict__ src1, const float* __restrict__ ea1,
    const int* __restrict__ rs0, const int* __restrict__ rs1,
    int* __restrict__ cur0, int* __restrict__ cur1,
    int* __restrict__ csrsrc0, int* __restrict__ csrsrc1,
    short* __restrict__ eas0, short* __restrict__ eas1) {
    int e = blockIdx.x * 256 + threadIdx.x;
    if (e < E_AA) {
        int d = dst0[e];
        int pos = atomicAdd(&cur0[d], 1);
        int slot = rs0[d] + pos;
        csrsrc0[slot] = src0[e];
        float4 a = ((const float4*)ea0)[(size_t)e * 2];
        float4 b = ((const float4*)ea0)[(size_t)e * 2 + 1];
        bf16x8 pk;
        pk[0] = f2bf(a.x); pk[1] = f2bf(a.y); pk[2] = f2bf(a.z); pk[3] = f2bf(a.w);
        pk[4] = f2bf(b.x); pk[5] = f2bf(b.y); pk[6] = f2bf(b.z); pk[7] = f2bf(b.w);
        *(bf16x8*)(eas0 + (size_t)slot * 8) = pk;
    }
    if (e < E_AS) {
        int d = dst1[e];
        int pos = atomicAdd(&cur1[d], 1);
        int slot = rs1[d] + pos;
        csrsrc1[slot] = src1[e];
        float4 a = ((const float4*)ea1)[(size_t)e * 2];
        float4 b = ((const float4*)ea1)[(size_t)e * 2 + 1];
        bf16x8 pk;
        pk[0] = f2bf(a.x); pk[1] = f2bf(a.y); pk[2] = f2bf(a.z); pk[3] = f2bf(a.w);
        pk[4] = f2bf(b.x); pk[5] = f2bf(b.y); pk[6] = f2bf(b.z); pk[7] = f2bf(b.w);
        *(bf16x8*)(eas1 + (size_t)slot * 8) = pk;
    }
}

// ---- degree counting-sort (LDS hist, both node types per dispatch) ----

__global__ __launch_bounds__(256) void deghist2_k(const int* __restrict__ rs0, int n0,
                                                  const int* __restrict__ rs1, int n1,
                                                  int nb0, int* __restrict__ dh0,
                                                  int* __restrict__ dh1) {
    int b = blockIdx.x;
    const int* rs; int n; int* dh; int lb;
    if ((int)b < nb0) { rs = rs0; n = n0; dh = dh0; lb = b; }
    else { rs = rs1; n = n1; dh = dh1; lb = b - nb0; }
    __shared__ int lh[256];
    int t = threadIdx.x;
    lh[t] = 0;
    __syncthreads();
    int d = lb * 256 + t;
    if (d < n) {
        int deg = rs[d + 1] - rs[d];
        if (deg > 255) deg = 255;
        atomicAdd(&lh[deg], 1);
    }
    __syncthreads();
    if (lh[t]) atomicAdd(&dh[t], lh[t]);
}

__global__ void binscan2_k(const int* __restrict__ dh0, const int* __restrict__ dh1,
                           int* __restrict__ dbo0, int* __restrict__ dbo1) {
    int w = threadIdx.x >> 6, lane = threadIdx.x & 63;
    const int* dh = w ? dh1 : dh0;
    int* dbo = w ? dbo1 : dbo0;
    int v[4]; int s = 0;
    #pragma unroll
    for (int i = 0; i < 4; ++i) { v[i] = dh[lane * 4 + i]; s += v[i]; }
    int incl = s;
    #pragma unroll
    for (int off = 1; off < 64; off <<= 1) {
        int u = __shfl_up(incl, off, 64);
        if (lane >= off) incl += u;
    }
    int run = incl - s;
    #pragma unroll
    for (int i = 0; i < 4; ++i) { dbo[lane * 4 + i] = run; run += v[i]; }
}

// R9: emit job table {d, row_start, cnt, 0} in LPT position — one 16B load in agg
// replaces the serial perm->rs dependent chain.
__global__ __launch_bounds__(256) void degscatter2_k(const int* __restrict__ rs0, int n0,
                                                     const int* __restrict__ rs1, int n1,
                                                     int nb0,
                                                     const int* __restrict__ dbo0,
                                                     const int* __restrict__ dbo1,
                                                     int* __restrict__ dcur0,
                                                     int* __restrict__ dcur1,
                                                     int4* __restrict__ jobs0,
                                                     int4* __restrict__ jobs1) {
    int b = blockIdx.x;
    const int* rs; int n; const int* dbo; int* dcur; int4* jobs; int lb;
    if ((int)b < nb0) { rs = rs0; n = n0; dbo = dbo0; dcur = dcur0; jobs = jobs0; lb = b; }
    else { rs = rs1; n = n1; dbo = dbo1; dcur = dcur1; jobs = jobs1; lb = b - nb0; }
    __shared__ int lh[256];
    __shared__ int lbase[256];
    int t = threadIdx.x;
    lh[t] = 0;
    __syncthreads();
    int d = lb * 256 + t;
    int deg = 0, lpos = 0, e0 = 0, degc = 0;
    if (d < n) {
        e0 = rs[d];
        deg = rs[d + 1] - e0;
        degc = deg > 255 ? 255 : deg;
        lpos = atomicAdd(&lh[degc], 1);
    }
    __syncthreads();
    int cnt = lh[t];
    if (cnt) lbase[t] = atomicAdd(&dcur[t], cnt);
    __syncthreads();
    if (d < n) jobs[dbo[degc] + lbase[degc] + lpos] = make_int4(d, e0, deg, 0);
}

// ---------------- MFMA quad GEMM (all outputs bf16) ----------------
// R8: 4x A-reuse. R10: AA split by weight matrix. R12: operand swap -> C^T,
// short4 packed stores (32 store-inst/wave vs 128).

__global__ __launch_bounds__(256) void gemm4_k(
    const short* __restrict__ Xb, const short* __restrict__ Xsb,
    const short* __restrict__ Wt,
    short* __restrict__ Y0b, short* __restrict__ Y1b, short* __restrict__ Y2b,
    short* __restrict__ Y3b, int gM) {
    int t = threadIdx.x;
    int wave = t >> 6, lane = t & 63;
    int quad = lane >> 4, l16 = lane & 15;
    int gM3 = gM * 3;
    bool style = (int)blockIdx.x >= gM3;
    const short* X = style ? Xsb : Xb;
    int rblk, w;
    if (style) { rblk = (int)blockIdx.x - gM3; w = 3; }
    else { w = (int)blockIdx.x / gM; rblk = (int)blockIdx.x % gM; }
    int rbase = rblk * 256 + wave * 64;

    bf16x8 xf[4][4];
    #pragma unroll
    for (int rt = 0; rt < 4; ++rt) {
        const short* xrow = X + (size_t)(rbase + rt * 16 + l16) * 128 + quad * 8;
        #pragma unroll
        for (int kb = 0; kb < 4; ++kb) xf[rt][kb] = *(const bf16x8*)(xrow + kb * 32);
    }

    short* Y = style ? Y3b : (w == 0 ? Y0b : (w == 1 ? Y1b : Y2b));
    int nlim = style ? NS : NA;
    const short* Wb = Wt + (size_t)w * 16384;
    #pragma unroll 2
    for (int nt = 0; nt < 8; ++nt) {
        const short* wrow = Wb + (size_t)(nt * 16 + l16) * 128 + quad * 8;
        bf16x8 wf[4];
        #pragma unroll
        for (int kb = 0; kb < 4; ++kb) wf[kb] = *(const bf16x8*)(wrow + kb * 32);
        f32x4 acc[4] = {{0,0,0,0},{0,0,0,0},{0,0,0,0},{0,0,0,0}};
        #pragma unroll
        for (int kb = 0; kb < 4; ++kb)
            #pragma unroll
            for (int rt = 0; rt < 4; ++rt)
                acc[rt] = __builtin_amdgcn_mfma_f32_16x16x32_bf16(wf[kb], xf[rt][kb],
                                                                  acc[rt], 0, 0, 0);
        #pragma unroll
        for (int rt = 0; rt < 4; ++rt) {
            int node = rbase + rt * 16 + l16;
            if (node < nlim) {
                short4 s;
                s.x = f2bf(acc[rt][0]); s.y = f2bf(acc[rt][1]);
                s.z = f2bf(acc[rt][2]); s.w = f2bf(acc[rt][3]);
                *(short4*)(Y + (size_t)node * 128 + nt * 16 + quad * 4) = s;
            }
        }
    }
}

// ---------------- fused GATv2 aggregation — R6 STATIC SCHEDULE + 4 blk/CU (R17) ----
// 4 dst/wave, 16 lanes/dst. R6-exact static 16-dst-chunk stride (best known;
// steal/snake variants all regressed — R7/R8/R9).
// R17 single-variable change: launch_bounds (256,2) -> (256,4). The kernel's
// natural allocation is exactly 128 VGPR (= the 4-wave/SIMD budget), so this
// should compile spill-free and double resident waves 8->16/CU, attacking the
// measured latency stall (VALUBusy 60%, Occupancy 17.6%). R4's spill disaster
// was a fatter kernel (in-loop segment switch); spill signature to watch:
// VGPR_Count < 128 or WRITE_SIZE explosion.

template<bool RELU>
__global__ __launch_bounds__(256, 4) void agg2_k(
    const short* __restrict__ xl0, const short* __restrict__ xr0,
    const short* __restrict__ eas0, const int* __restrict__ csrsrc0,
    const float* __restrict__ We0, const float* __restrict__ att0,
    const float* __restrict__ bias0, const int4* __restrict__ jobs0,
    float* __restrict__ out0, short* __restrict__ outb0, int nd0, int nblk0,
    const short* __restrict__ xl1, const short* __restrict__ xr1,
    const short* __restrict__ eas1, const int* __restrict__ csrsrc1,
    const float* __restrict__ We1, const float* __restrict__ att1,
    const float* __restrict__ bias1, const int4* __restrict__ jobs1,
    float* __restrict__ out1, short* __restrict__ outb1, int nd1, int nblk1,
    int nblkB0) {

    int wave = threadIdx.x >> 6;
    int lane = threadIdx.x & 63;
    int g = lane >> 4;
    int sl = lane & 15;
    int c = sl * 8;

    // static partition: which segment does this block serve?
    const short* xl; const short* xrp; const short* eas; const int* csrsrc;
    const float* We; const float* att; const float* bias;
    const int4* jobs;
    float* out; short* outb; int ndst, nblk, blk, stride;
    if ((int)blockIdx.x < nblkB0) {
        xl = xl0; xrp = xr0; eas = eas0; csrsrc = csrsrc0; We = We0; att = att0; bias = bias0;
        jobs = jobs0; out = out0; outb = outb0; ndst = nd0; nblk = nblk0;
        blk = blockIdx.x; stride = nblkB0;
    } else {
        xl = xl1; xrp = xr1; eas = eas1; csrsrc = csrsrc1; We = We1; att = att1; bias = bias1;
        jobs = jobs1; out = out1; outb = outb1; ndst = nd1; nblk = nblk1;
        blk = blockIdx.x - nblkB0; stride = gridDim.x - nblkB0;
    }
    if (blk >= nblk) return;

    // per-segment invariants, pinned in VGPRs (loaded exactly once per block)
    float4 WeA[8], WeB[8];
    #pragma unroll
    for (int k = 0; k < 8; ++k) {
        WeA[k] = *(const float4*)(We + k * 128 + c);
        WeB[k] = *(const float4*)(We + k * 128 + c + 4);
    }
    float4 attA = *(const float4*)(att + c);
    float4 attB = *(const float4*)(att + c + 4);
    float4 bA = *(const float4*)(bias + c);
    float4 bB = *(const float4*)(bias + c + 4);
    #pragma unroll
    for (int k = 0; k < 8; ++k) {
        asm volatile("" : "+v"(WeA[k].x), "+v"(WeA[k].y), "+v"(WeA[k].z), "+v"(WeA[k].w));
        asm volatile("" : "+v"(WeB[k].x), "+v"(WeB[k].y), "+v"(WeB[k].z), "+v"(WeB[k].w));
    }
    asm volatile("" : "+v"(attA.x), "+v"(attA.y), "+v"(attA.z), "+v"(attA.w));
    asm volatile("" : "+v"(attB.x), "+v"(attB.y), "+v"(attB.z), "+v"(attB.w));

    auto load_job = [&](int b) -> int4 {
        int di = b * 16 + wave * 4 + g;
        bool h = di < ndst;
        int4 j = jobs[h ? (ndst - 1 - di) : 0];   // LPT: heaviest first
        if (!h) j.z = 0;
        j.w = h ? 1 : 0;
        return j;
    };

    // group-level pipeline: job + xr row for the first group
    int4 jb = load_job(blk);
    bf16x8 xrb = *(const bf16x8*)(xrp + (size_t)jb.x * 128 + c);

    for (; blk < nblk; blk += stride) {
        int nb = blk + stride;
        int4 jbN = (nb < nblk) ? load_job(nb) : make_int4(0, 0, 0, 0);

        int d = jb.x, e0 = jb.y, cnt = jb.z;
        bool has = jb.w != 0;
        float4 xrA = bfh2f4(xrb, 0), xrB = bfh2f4(xrb, 1);

        float4 accA = {0,0,0,0}, accB = {0,0,0,0};
        float den = 0.f, mrun = -INFINITY;
        int last = (cnt > 0) ? e0 + cnt - 1 : 0;

        int mc = cnt;
        mc = max(mc, __shfl_xor(mc, 16, 64));
        mc = max(mc, __shfl_xor(mc, 32, 64));
        int niter = (mc + 3) >> 2;

        auto lds_idx = [&](int ib, int* s) {
            #pragma unroll
            for (int j = 0; j < 4; ++j) {
                int cj = (ib + j < last) ? ib + j : last;
                s[j] = csrsrc[cj];
            }
        };
        auto lds_ea = [&](int ib, bf16x8* ea) {
            #pragma unroll
            for (int j = 0; j < 4; ++j) {
                int cj = (ib + j < last) ? ib + j : last;
                ea[j] = *(const bf16x8*)(eas + (size_t)cj * 8);
            }
        };
        auto lds_x = [&](const int* s, bf16x8* xb) {
            #pragma unroll
            for (int j = 0; j < 4; ++j)
                xb[j] = *(const bf16x8*)(xl + (size_t)s[j] * 128 + c);
        };

        int sA[4], sB[4];
        bf16x8 xbA[4], xbB[4], eaA[4], eaB[4];

        if (niter > 0) {
            int st[4];
            lds_idx(e0, st);
            lds_ea(e0, eaA);
            lds_x(st, xbA);
            lds_idx(e0 + 4, sA);
        }

        auto step = [&](int i, bf16x8 (&xbC)[4], bf16x8 (&eaC)[4], int (&sNx)[4],
                        bf16x8 (&xbN)[4], bf16x8 (&eaN)[4], int (&sN2)[4]) {
            lds_x(sNx, xbN);
            lds_ea(e0 + i + 4, eaN);
            lds_idx(e0 + i + 8, sN2);

            float4 x0A = bfh2f4(xbC[0], 0), x0B = bfh2f4(xbC[0], 1);
            float4 x1A = bfh2f4(xbC[1], 0), x1B = bfh2f4(xbC[1], 1);
            float4 x2A = bfh2f4(xbC[2], 0), x2B = bfh2f4(xbC[2], 1);
            float4 x3A = bfh2f4(xbC[3], 0), x3B = bfh2f4(xbC[3], 1);

            auto logit = [&](float4 xA, float4 xB, bf16x8 eab) -> float {
                float4 ea = bfh2f4(eab, 0), eb = bfh2f4(eab, 1);
                float4 mA = f4add(xA, xrA), mB = f4add(xB, xrB);
                mA = f4fma(ea.x, WeA[0], mA); mB = f4fma(ea.x, WeB[0], mB);
                mA = f4fma(ea.y, WeA[1], mA); mB = f4fma(ea.y, WeB[1], mB);
                mA = f4fma(ea.z, WeA[2], mA); mB = f4fma(ea.z, WeB[2], mB);
                mA = f4fma(ea.w, WeA[3], mA); mB = f4fma(ea.w, WeB[3], mB);
                mA = f4fma(eb.x, WeA[4], mA); mB = f4fma(eb.x, WeB[4], mB);
                mA = f4fma(eb.y, WeA[5], mA); mB = f4fma(eb.y, WeB[5], mB);
                mA = f4fma(eb.z, WeA[6], mA); mB = f4fma(eb.z, WeB[6], mB);
                mA = f4fma(eb.w, WeA[7], mA); mB = f4fma(eb.w, WeB[7], mB);
                return f4dot(f4leaky(mA), attA) + f4dot(f4leaky(mB), attB);
            };

            float t0 = logit(x0A, x0B, eaC[0]);
            float t1 = logit(x1A, x1B, eaC[1]);
            float t2 = logit(x2A, x2B, eaC[2]);
            float t3 = logit(x3A, x3B, eaC[3]);
            #pragma unroll
            for (int off = 8; off; off >>= 1) {
                t0 += __shfl_xor(t0, off, 64);
                t1 += __shfl_xor(t1, off, 64);
                t2 += __shfl_xor(t2, off, 64);
                t3 += __shfl_xor(t3, off, 64);
            }
            if (i + 1 >= cnt) t1 = -INFINITY;
            if (i + 2 >= cnt) t2 = -INFINITY;
            if (i + 3 >= cnt) t3 = -INFINITY;

            if (i < cnt) {
                float m4 = fmaxf(fmaxf(t0, t1), fmaxf(t2, t3));
                float nm = fmaxf(mrun, m4);
                float sc = __expf(mrun - nm);
                float p0 = __expf(t0 - nm);
                float p1 = __expf(t1 - nm);
                float p2 = __expf(t2 - nm);
                float p3 = __expf(t3 - nm);
                den = den * sc + p0 + p1 + p2 + p3;
                accA = f4mix(sc, accA, p0, x0A);
                accA = f4fma(p1, x1A, accA);
                accA = f4fma(p2, x2A, accA);
                accA = f4fma(p3, x3A, accA);
                accB = f4mix(sc, accB, p0, x0B);
                accB = f4fma(p1, x1B, accB);
                accB = f4fma(p2, x2B, accB);
                accB = f4fma(p3, x3B, accB);
                mrun = nm;
            }
        };

        int it = 0;
        for (; it + 1 < niter; it += 2) {
            step(it * 4,     xbA, eaA, sA, xbB, eaB, sB);
            step(it * 4 + 4, xbB, eaB, sB, xbA, eaA, sA);
        }
        if (it < niter)
            step(it * 4, xbA, eaA, sA, xbB, eaB, sB);

        float inv = 1.f / fmaxf(den, 1e-16f);
        float4 oA = make_float4(accA.x * inv + bA.x, accA.y * inv + bA.y,
                                accA.z * inv + bA.z, accA.w * inv + bA.w);
        float4 oB = make_float4(accB.x * inv + bB.x, accB.y * inv + bB.y,
                                accB.z * inv + bB.z, accB.w * inv + bB.w);
        if (RELU) {
            oA = make_float4(fmaxf(oA.x,0.f), fmaxf(oA.y,0.f),
                             fmaxf(oA.z,0.f), fmaxf(oA.w,0.f));
            oB = make_float4(fmaxf(oB.x,0.f), fmaxf(oB.y,0.f),
                             fmaxf(oB.z,0.f), fmaxf(oB.w,0.f));
        }
        float ss = f4dot(oA, oA) + f4dot(oB, oB);
        #pragma unroll
        for (int off = 8; off; off >>= 1) ss += __shfl_xor(ss, off, 64);
        float innv = 1.f / fmaxf(sqrtf(ss), 1e-12f);
        oA = make_float4(oA.x * innv, oA.y * innv, oA.z * innv, oA.w * innv);
        oB = make_float4(oB.x * innv, oB.y * innv, oB.z * innv, oB.w * innv);
        if (has) {
            if (out) {
                float4* op = (float4*)(out + (size_t)d * 128 + c);
                op[0] = oA;
                op[1] = oB;
            }
            if (outb) {
                bf16x8 pk;
                pk[0] = f2bf(oA.x); pk[1] = f2bf(oA.y); pk[2] = f2bf(oA.z); pk[3] = f2bf(oA.w);
                pk[4] = f2bf(oB.x); pk[5] = f2bf(oB.y); pk[6] = f2bf(oB.z); pk[7] = f2bf(oB.w);
                *(bf16x8*)(outb + (size_t)d * 128 + c) = pk;
            }
        }

        // prefetch next chunk's xr row (hides under next chunk's gather chain)
        bf16x8 xrbN = *(const bf16x8*)(xrp + (size_t)jbN.x * 128 + c);
        jb = jbN;
        xrb = xrbN;
    }
}

// ---------------- launch ----------------

extern "C" void kernel_launch(void* const* d_in, const int* in_sizes, int n_in,
                              void* d_out, int out_size, void* d_ws, size_t ws_size,
                              hipStream_t stream) {
    const float* x_artist = (const float*)d_in[0];
    const float* x_style  = (const float*)d_in[1];
    const int*   src_aa   = (const int*)d_in[2];
    const int*   dst_aa   = (const int*)d_in[3];
    const float* eattr_aa = (const float*)d_in[4];
    const int*   src_as   = (const int*)d_in[5];
    const int*   dst_as   = (const int*)d_in[6];
    const float* eattr_as = (const float*)d_in[7];
    const float* Wl0_aa = (const float*)d_in[8];
    const float* Wr0_aa = (const float*)d_in[9];
    const float* att0_aa = (const float*)d_in[10];
    const float* We0_aa = (const float*)d_in[11];
    const float* b0_aa = (const float*)d_in[12];
    const float* Wl0_as = (const float*)d_in[13];
    const float* Wr0_as = (const float*)d_in[14];
    const float* att0_as = (const float*)d_in[15];
    const float* We0_as = (const float*)d_in[16];
    const float* b0_as = (const float*)d_in[17];
    const float* Wl_aa = (const float*)d_in[18];
    const float* Wr_aa = (const float*)d_in[19];
    const float* att_aa = (const float*)d_in[20];
    const float* We_aa = (const float*)d_in[21];
    const float* b_aa = (const float*)d_in[22];
    const float* Wl_as = (const float*)d_in[23];
    const float* Wr_as = (const float*)d_in[24];
    const float* att_as = (const float*)d_in[25];
    const float* We_as = (const float*)d_in[26];
    const float* b_as = (const float*)d_in[27];

    float* out = (float*)d_out;

    // ws layout: bf16 regions, then int regions
    short* Xb    = (short*)d_ws;                       // [NAPAD][128]
    short* Xsb   = Xb + (size_t)NAPAD * 128;           // [NSPAD][128]
    short* Wt    = Xsb + (size_t)NSPAD * 128;          // [3][4][128][128]
    short* bufAb = Wt + 12 * 16384;                    // xl_aa
    short* bufDb = bufAb + (size_t)NA * 128;           // xl_as
    short* bufBb = bufDb + (size_t)NA * 128;           // xr_aa
    short* bufCb = bufBb + (size_t)NA * 128;           // xr_as
    short* easAA = bufCb + (size_t)NSPAD * 128;        // [E_AA][8]
    short* easAS = easAA + (size_t)E_AA * 8;           // [E_AS][8]
    int* ip = (int*)(easAS + (size_t)E_AS * 8);        // 16B-aligned
    // zeroed zone
    int* zbase  = ip;
    int* deg_aa = ip;            ip += NA;
    int* cur_aa = ip;            ip += NA;
    int* deg_as = ip;            ip += NS;
    int* cur_as = ip;            ip += NS;
    int* dh_aa  = ip;            ip += 256;
    int* dh_as  = ip;            ip += 256;
    int* dcur_aa = ip;           ip += 256;
    int* dcur_as = ip;           ip += 256;
    size_t zbytes = (size_t)(ip - zbase) * sizeof(int);
    // non-zeroed (jobs first: int4-aligned — zero zone stays 16B-multiple)
    int4* jobs_aa = (int4*)ip;   ip += 4 * NA;
    int4* jobs_as = (int4*)ip;   ip += 4 * NS;
    int* rs_aa  = ip;            ip += NA + 1;
    int* rs_as  = ip;            ip += NS + 1;
    int* csrsrc_aa = ip;         ip += E_AA;
    int* csrsrc_as = ip;         ip += E_AS;
    int* dbo_aa = ip;            ip += 256;
    int* dbo_as = ip;            ip += 256;
    int* bsum   = ip;            ip += 64;

    const int nbA_scan = (NA + SCAN_CH - 1) / SCAN_CH;
    const int nbS_scan = (NS + SCAN_CH - 1) / SCAN_CH;
    const int nbA_node = (NA + 255) / 256;
    const int nbS_node = (NS + 255) / 256;
    const int gE = (E_AA + 255) / 256;                   // 1954
    const int gCvt = (NAPAD * 32 + NSPAD * 32 + 255) / 256;
    const int gWtr = 12 * 64;

    // ---- preprocessing ----
    hipMemsetAsync(zbase, 0, zbytes, stream);
    prep1_k<<<gE + gCvt + gWtr, 256, 0, stream>>>(
        dst_aa, dst_as, deg_aa, deg_as,
        x_artist, x_style, Xb, Xsb,
        Wl0_aa, Wr0_aa, Wl0_as, Wr0_as, Wl_aa, Wr_aa, Wl_as, Wr_as, Wt,
        gE, gCvt);
    scanA_k<<<nbA_scan + nbS_scan, 256, 0, stream>>>(deg_aa, NA, deg_as, NS, nbA_scan, bsum);
    scanB_k<<<1, 64, 0, stream>>>(bsum, nbA_scan, nbS_scan);
    scanC_k<<<nbA_scan + nbS_scan, 256, 0, stream>>>(deg_aa, NA, deg_as, NS, nbA_scan,
                                                     bsum, rs_aa, rs_as);
    scatter2_k<<<gE, 256, 0, stream>>>(dst_aa, src_aa, eattr_aa,
                                       dst_as, src_as, eattr_as,
                                       rs_aa, rs_as, cur_aa, cur_as,
                                       csrsrc_aa, csrsrc_as, easAA, easAS);
    deghist2_k<<<nbA_node + nbS_node, 256, 0, stream>>>(rs_aa, NA, rs_as, NS, nbA_node,
                                                        dh_aa, dh_as);
    binscan2_k<<<1, 128, 0, stream>>>(dh_aa, dh_as, dbo_aa, dbo_as);
    degscatter2_k<<<nbA_node + nbS_node, 256, 0, stream>>>(rs_aa, NA, rs_as, NS, nbA_node,
                                                           dbo_aa, dbo_as, dcur_aa, dcur_as,
                                                           jobs_aa, jobs_as);

    const int gM = NAPAD / 256;       // 196
    const int gS4 = NSPAD / 256;      // 20
    const int aggA = (NA + 15) / 16;  // 3125 dst-chunks
    const int aggS = (NS + 15) / 16;  // 313

    for (int layer = 0; layer < 3; ++layer) {
        int j = layer - 1;
        const float *patt_aa, *pWe_aa, *pb_aa, *patt_as, *pWe_as, *pb_as;
        if (layer == 0) {
            patt_aa = att0_aa; pWe_aa = We0_aa; pb_aa = b0_aa;
            patt_as = att0_as; pWe_as = We0_as; pb_as = b0_as;
        } else {
            patt_aa = att_aa + (size_t)j * CDIM;
            pWe_aa = We_aa + (size_t)j * ED * CDIM;
            pb_aa = b_aa + (size_t)j * CDIM;
            patt_as = att_as + (size_t)j * CDIM;
            pWe_as = We_as + (size_t)j * ED * CDIM;
            pb_as = b_as + (size_t)j * CDIM;
        }
        const short* pWt = Wt + (size_t)layer * 4 * 16384;
        float* hA_out = (layer == 2) ? out : nullptr;
        float* hS_out = (layer == 2) ? out + (size_t)NA * CDIM : nullptr;
        short* hA_outb = (layer == 2) ? nullptr : Xb;
        short* hS_outb = (layer == 2) ? nullptr : Xsb;

        gemm4_k<<<3 * gM + gS4, 256, 0, stream>>>(Xb, Xsb, pWt, bufAb, bufBb, bufDb, bufCb, gM);

        if (layer < 2)
            agg2_k<true><<<AGG_BLOCKS, 256, 0, stream>>>(
                bufAb, bufBb, easAA, csrsrc_aa, pWe_aa, patt_aa, pb_aa,
                jobs_aa, hA_out, hA_outb, NA, aggA,
                bufDb, bufCb, easAS, csrsrc_as, pWe_as, patt_as, pb_as,
                jobs_as, hS_out, hS_outb, NS, aggS, AGG_BLK_AA);
        else
            agg2_k<false><<<AGG_BLOCKS, 256, 0, stream>>>(
                bufAb, bufBb, easAA, csrsrc_aa, pWe_aa, patt_aa, pb_aa,
                jobs_aa, hA_out, hA_outb, NA, aggA,
                bufDb, bufCb, easAS, csrsrc_as, pWe_as, patt_as, pb_as,
                jobs_as, hS_out, hS_outb, NS, aggS, AGG_BLK_AA);
    }
}

// Round 12
// 496.573 us; speedup vs baseline: 4.6828x; 4.6828x over previous
//
#include <hip/hip_runtime.h>
#include <hip/hip_bf16.h>
#include <math.h>

#define NA 50000
#define NS 5000
#define E_AA 500000
#define E_AS 250000
#define CDIM 128
#define ED 8
#define NAPAD 50176   // 196*256
#define NSPAD 5120    // 20*256
#define SCAN_CH 2048  // elements per scan block (256 thr x 8)
#define AGG_BLOCKS 1024
#define AGG_BLK_AA 711   // R6-proven split: AA 500k/711, AS 250k/313

typedef __attribute__((ext_vector_type(8))) short bf16x8;
typedef __attribute__((ext_vector_type(4))) float f32x4;

__device__ inline short f2bf(float f) {
    __hip_bfloat16 h = __float2bfloat16(f);
    return *(short*)&h;
}
__device__ inline float bf2f(short s) {
    union { unsigned int u; float f; } cv;
    cv.u = ((unsigned int)(unsigned short)s) << 16;
    return cv.f;
}

// ---------------- small helpers ----------------

__device__ inline float4 f4fma(float s, float4 a, float4 b) {
    return make_float4(fmaf(s, a.x, b.x), fmaf(s, a.y, b.y),
                       fmaf(s, a.z, b.z), fmaf(s, a.w, b.w));
}
__device__ inline float f4dot(float4 a, float4 b) {
    return a.x * b.x + a.y * b.y + a.z * b.z + a.w * b.w;
}
__device__ inline float4 bfh2f4(bf16x8 v, int half) {
    int o = half * 4;
    return make_float4(bf2f(v[o]), bf2f(v[o + 1]), bf2f(v[o + 2]), bf2f(v[o + 3]));
}

// R18: native-vector math for the agg hot loop — f32x4 expressions lower to
// llvm.fmuladd.v4f32 / elementwise max-min, which gfx950 ISel maps onto
// VOP3P packed-fp32 (v_pk_fma_f32 / v_pk_max_f32): 2 lanes per instruction,
// halving the ~96 VALU ops per edge that dominate VALUBusy.
__device__ inline f32x4 bfh2v4(bf16x8 v, int half) {
    int o = half * 4;
    f32x4 r = { bf2f(v[o]), bf2f(v[o + 1]), bf2f(v[o + 2]), bf2f(v[o + 3]) };
    return r;
}
__device__ inline f32x4 v4leaky(f32x4 a) {
    f32x4 z = { 0.f, 0.f, 0.f, 0.f };
    return __builtin_elementwise_max(a, z) + 0.2f * __builtin_elementwise_min(a, z);
}
__device__ inline float v4dot(f32x4 a, f32x4 b) {
    f32x4 p = a * b;
    return (p.x + p.y) + (p.z + p.w);
}
__device__ inline f32x4 v4max0(f32x4 a) {
    f32x4 z = { 0.f, 0.f, 0.f, 0.f };
    return __builtin_elementwise_max(a, z);
}

// ---------------- fused prep: count degrees + cvt inputs + weight transpose (R12) ----

__global__ __launch_bounds__(256) void prep1_k(
    const int* __restrict__ dst0, const int* __restrict__ dst1,
    int* __restrict__ deg0, int* __restrict__ deg1,
    const float* __restrict__ xa, const float* __restrict__ xs,
    short* __restrict__ Xb, short* __restrict__ Xsb,
    const float* __restrict__ Wl0_aa, const float* __restrict__ Wr0_aa,
    const float* __restrict__ Wl0_as, const float* __restrict__ Wr0_as,
    const float* __restrict__ Wl_aa, const float* __restrict__ Wr_aa,
    const float* __restrict__ Wl_as, const float* __restrict__ Wr_as,
    short* __restrict__ Wt, int gCnt, int gCvt) {
    int b = blockIdx.x;
    if (b < gCnt) {
        int e = b * 256 + threadIdx.x;
        if (e < E_AA) atomicAdd(&deg0[dst0[e]], 1);
        if (e < E_AS) atomicAdd(&deg1[dst1[e]], 1);
        return;
    }
    b -= gCnt;
    if (b < gCvt) {
        const int t4A = NAPAD * 32;
        const int t4S = NSPAD * 32;
        int i = b * 256 + threadIdx.x;
        if (i < t4A) {
            int row = i >> 5, c4 = i & 31;
            float4 v = make_float4(0.f, 0.f, 0.f, 0.f);
            if (row < NA) v = ((const float4*)xa)[(size_t)row * 32 + c4];
            short4 s;
            s.x = f2bf(v.x); s.y = f2bf(v.y); s.z = f2bf(v.z); s.w = f2bf(v.w);
            ((short4*)Xb)[i] = s;
        } else if (i < t4A + t4S) {
            int j = i - t4A;
            int row = j >> 5, c4 = j & 31;
            float4 v = make_float4(0.f, 0.f, 0.f, 0.f);
            if (row < NS && c4 < 16) v = ((const float4*)xs)[(size_t)row * 16 + c4];
            short4 s;
            s.x = f2bf(v.x); s.y = f2bf(v.y); s.z = f2bf(v.z); s.w = f2bf(v.w);
            ((short4*)Xsb)[j] = s;
        }
        return;
    }
    b -= gCvt;
    {
        int mat = b >> 6;            // 0..11
        int layer = mat >> 2, w = mat & 3;
        int idx = (b & 63) * 256 + threadIdx.x;  // k*128+n
        int k = idx >> 7, n = idx & 127;
        const float* W;
        int K = 128;
        if (layer == 0) {
            W = (w == 0) ? Wl0_aa : (w == 1) ? Wr0_aa : (w == 2) ? Wl0_as : Wr0_as;
            if (w == 3) K = 64;
        } else {
            int j = layer - 1;
            W = ((w == 0) ? Wl_aa : (w == 1) ? Wr_aa : (w == 2) ? Wl_as : Wr_as)
                + (size_t)j * 16384;
        }
        float v = (k < K) ? W[(size_t)k * 128 + n] : 0.f;
        Wt[(size_t)mat * 16384 + n * 128 + k] = f2bf(v);
    }
}

// phase A: per-block sums of deg (two concatenated arrays)
__global__ __launch_bounds__(256) void scanA_k(const int* __restrict__ deg0, int n0,
                                               const int* __restrict__ deg1, int n1,
                                               int nb0, int* __restrict__ bsum) {
    int b = blockIdx.x;
    const int* deg; int n; int lb;
    if ((int)b < nb0) { deg = deg0; n = n0; lb = b; }
    else { deg = deg1; n = n1; lb = b - nb0; }
    int t = threadIdx.x;
    int base = lb * SCAN_CH + t * 8;
    int s = 0;
    #pragma unroll
    for (int i = 0; i < 8; ++i) { int idx = base + i; s += (idx < n) ? deg[idx] : 0; }
    int lane = t & 63, w = t >> 6;
    #pragma unroll
    for (int off = 1; off < 64; off <<= 1) {
        int u = __shfl_up(s, off, 64);
        if (lane >= off) s += u;
    }
    __shared__ int ws[4];
    if (lane == 63) ws[w] = s;
    __syncthreads();
    if (t == 0) bsum[blockIdx.x] = ws[0] + ws[1] + ws[2] + ws[3];
}

// phase B: exclusive-scan the block sums (two segments) in one wave
__global__ void scanB_k(int* __restrict__ bsum, int nb0, int nb1) {
    int t = threadIdx.x;   // 64
    int n = nb0 + nb1;
    int v = (t < n) ? bsum[t] : 0;
    int incl = v;
    #pragma unroll
    for (int off = 1; off < 64; off <<= 1) {
        int u = __shfl_up(incl, off, 64);
        if (t >= off) incl += u;
    }
    int excl = incl - v;
    int sum0 = __shfl(incl, nb0 - 1, 64);
    if (t >= nb0) excl -= sum0;
    if (t < n) bsum[t] = excl;
}

// phase C: block-local prefix + global offset -> row_start (exclusive), plus rs[n]
__global__ __launch_bounds__(256) void scanC_k(const int* __restrict__ deg0, int n0,
                                               const int* __restrict__ deg1, int n1,
                                               int nb0, const int* __restrict__ bsum,
                                               int* __restrict__ rs0, int* __restrict__ rs1) {
    int b = blockIdx.x;
    const int* deg; int n; int* rs; int lb;
    if ((int)b < nb0) { deg = deg0; n = n0; rs = rs0; lb = b; }
    else { deg = deg1; n = n1; rs = rs1; lb = b - nb0; }
    int boff = bsum[b];
    int t = threadIdx.x;
    int base = lb * SCAN_CH + t * 8;
    int v[8];
    int tsum = 0;
    #pragma unroll
    for (int i = 0; i < 8; ++i) {
        int idx = base + i;
        v[i] = (idx < n) ? deg[idx] : 0;
        tsum += v[i];
    }
    int lane = t & 63, w = t >> 6;
    int incl = tsum;
    #pragma unroll
    for (int off = 1; off < 64; off <<= 1) {
        int u = __shfl_up(incl, off, 64);
        if (lane >= off) incl += u;
    }
    __shared__ int ws[4];
    if (lane == 63) ws[w] = incl;
    __syncthreads();
    int woff = 0;
    for (int i = 0; i < w; ++i) woff += ws[i];
    int run = boff + woff + incl - tsum;
    #pragma unroll
    for (int i = 0; i < 8; ++i) {
        int idx = base + i;
        if (idx < n) {
            rs[idx] = run;
            run += v[i];
            if (idx == n - 1) rs[n] = run;
        }
    }
}

// scatter: build csr_src + CSR-ordered bf16 edge attrs (kills 1 gather hop in agg)
__global__ __launch_bounds__(256) void scatter2_k(
    const int* __restrict__ dst0, const int* __restrict__ src0, const float* __restrict__ ea0,
    const int* __restrict__ dst1, const int* __restrict__ src1, const float* __restrict__ ea1,
    const int* __restrict__ rs0, const int* __restrict__ rs1,
    int* __restrict__ cur0, int* __restrict__ cur1,
    int* __restrict__ csrsrc0, int* __restrict__ csrsrc1,
    short* __restrict__ eas0, short* __restrict__ eas1) {
    int e = blockIdx.x * 256 + threadIdx.x;
    if (e < E_AA) {
        int d = dst0[e];
        int pos = atomicAdd(&cur0[d], 1);
        int slot = rs0[d] + pos;
        csrsrc0[slot] = src0[e];
        float4 a = ((const float4*)ea0)[(size_t)e * 2];
        float4 b = ((const float4*)ea0)[(size_t)e * 2 + 1];
        bf16x8 pk;
        pk[0] = f2bf(a.x); pk[1] = f2bf(a.y); pk[2] = f2bf(a.z); pk[3] = f2bf(a.w);
        pk[4] = f2bf(b.x); pk[5] = f2bf(b.y); pk[6] = f2bf(b.z); pk[7] = f2bf(b.w);
        *(bf16x8*)(eas0 + (size_t)slot * 8) = pk;
    }
    if (e < E_AS) {
        int d = dst1[e];
        int pos = atomicAdd(&cur1[d], 1);
        int slot = rs1[d] + pos;
        csrsrc1[slot] = src1[e];
        float4 a = ((const float4*)ea1)[(size_t)e * 2];
        float4 b = ((const float4*)ea1)[(size_t)e * 2 + 1];
        bf16x8 pk;
        pk[0] = f2bf(a.x); pk[1] = f2bf(a.y); pk[2] = f2bf(a.z); pk[3] = f2bf(a.w);
        pk[4] = f2bf(b.x); pk[5] = f2bf(b.y); pk[6] = f2bf(b.z); pk[7] = f2bf(b.w);
        *(bf16x8*)(eas1 + (size_t)slot * 8) = pk;
    }
}

// ---- degree counting-sort (LDS hist, both node types per dispatch) ----

__global__ __launch_bounds__(256) void deghist2_k(const int* __restrict__ rs0, int n0,
                                                  const int* __restrict__ rs1, int n1,
                                                  int nb0, int* __restrict__ dh0,
                                                  int* __restrict__ dh1) {
    int b = blockIdx.x;
    const int* rs; int n; int* dh; int lb;
    if ((int)b < nb0) { rs = rs0; n = n0; dh = dh0; lb = b; }
    else { rs = rs1; n = n1; dh = dh1; lb = b - nb0; }
    __shared__ int lh[256];
    int t = threadIdx.x;
    lh[t] = 0;
    __syncthreads();
    int d = lb * 256 + t;
    if (d < n) {
        int deg = rs[d + 1] - rs[d];
        if (deg > 255) deg = 255;
        atomicAdd(&lh[deg], 1);
    }
    __syncthreads();
    if (lh[t]) atomicAdd(&dh[t], lh[t]);
}

__global__ void binscan2_k(const int* __restrict__ dh0, const int* __restrict__ dh1,
                           int* __restrict__ dbo0, int* __restrict__ dbo1) {
    int w = threadIdx.x >> 6, lane = threadIdx.x & 63;
    const int* dh = w ? dh1 : dh0;
    int* dbo = w ? dbo1 : dbo0;
    int v[4]; int s = 0;
    #pragma unroll
    for (int i = 0; i < 4; ++i) { v[i] = dh[lane * 4 + i]; s += v[i]; }
    int incl = s;
    #pragma unroll
    for (int off = 1; off < 64; off <<= 1) {
        int u = __shfl_up(incl, off, 64);
        if (lane >= off) incl += u;
    }
    int run = incl - s;
    #pragma unroll
    for (int i = 0; i < 4; ++i) { dbo[lane * 4 + i] = run; run += v[i]; }
}

// R9: emit job table {d, row_start, cnt, 0} in LPT position — one 16B load in agg
// replaces the serial perm->rs dependent chain.
__global__ __launch_bounds__(256) void degscatter2_k(const int* __restrict__ rs0, int n0,
                                                     const int* __restrict__ rs1, int n1,
                                                     int nb0,
                                                     const int* __restrict__ dbo0,
                                                     const int* __restrict__ dbo1,
                                                     int* __restrict__ dcur0,
                                                     int* __restrict__ dcur1,
                                                     int4* __restrict__ jobs0,
                                                     int4* __restrict__ jobs1) {
    int b = blockIdx.x;
    const int* rs; int n; const int* dbo; int* dcur; int4* jobs; int lb;
    if ((int)b < nb0) { rs = rs0; n = n0; dbo = dbo0; dcur = dcur0; jobs = jobs0; lb = b; }
    else { rs = rs1; n = n1; dbo = dbo1; dcur = dcur1; jobs = jobs1; lb = b - nb0; }
    __shared__ int lh[256];
    __shared__ int lbase[256];
    int t = threadIdx.x;
    lh[t] = 0;
    __syncthreads();
    int d = lb * 256 + t;
    int deg = 0, lpos = 0, e0 = 0, degc = 0;
    if (d < n) {
        e0 = rs[d];
        deg = rs[d + 1] - e0;
        degc = deg > 255 ? 255 : deg;
        lpos = atomicAdd(&lh[degc], 1);
    }
    __syncthreads();
    int cnt = lh[t];
    if (cnt) lbase[t] = atomicAdd(&dcur[t], cnt);
    __syncthreads();
    if (d < n) jobs[dbo[degc] + lbase[degc] + lpos] = make_int4(d, e0, deg, 0);
}

// ---------------- MFMA quad GEMM (all outputs bf16) ----------------
// R8: 4x A-reuse. R10: AA split by weight matrix. R12: operand swap -> C^T,
// short4 packed stores (32 store-inst/wave vs 128).

__global__ __launch_bounds__(256) void gemm4_k(
    const short* __restrict__ Xb, const short* __restrict__ Xsb,
    const short* __restrict__ Wt,
    short* __restrict__ Y0b, short* __restrict__ Y1b, short* __restrict__ Y2b,
    short* __restrict__ Y3b, int gM) {
    int t = threadIdx.x;
    int wave = t >> 6, lane = t & 63;
    int quad = lane >> 4, l16 = lane & 15;
    int gM3 = gM * 3;
    bool style = (int)blockIdx.x >= gM3;
    const short* X = style ? Xsb : Xb;
    int rblk, w;
    if (style) { rblk = (int)blockIdx.x - gM3; w = 3; }
    else { w = (int)blockIdx.x / gM; rblk = (int)blockIdx.x % gM; }
    int rbase = rblk * 256 + wave * 64;

    bf16x8 xf[4][4];
    #pragma unroll
    for (int rt = 0; rt < 4; ++rt) {
        const short* xrow = X + (size_t)(rbase + rt * 16 + l16) * 128 + quad * 8;
        #pragma unroll
        for (int kb = 0; kb < 4; ++kb) xf[rt][kb] = *(const bf16x8*)(xrow + kb * 32);
    }

    short* Y = style ? Y3b : (w == 0 ? Y0b : (w == 1 ? Y1b : Y2b));
    int nlim = style ? NS : NA;
    const short* Wb = Wt + (size_t)w * 16384;
    #pragma unroll 2
    for (int nt = 0; nt < 8; ++nt) {
        const short* wrow = Wb + (size_t)(nt * 16 + l16) * 128 + quad * 8;
        bf16x8 wf[4];
        #pragma unroll
        for (int kb = 0; kb < 4; ++kb) wf[kb] = *(const bf16x8*)(wrow + kb * 32);
        f32x4 acc[4] = {{0,0,0,0},{0,0,0,0},{0,0,0,0},{0,0,0,0}};
        #pragma unroll
        for (int kb = 0; kb < 4; ++kb)
            #pragma unroll
            for (int rt = 0; rt < 4; ++rt)
                acc[rt] = __builtin_amdgcn_mfma_f32_16x16x32_bf16(wf[kb], xf[rt][kb],
                                                                  acc[rt], 0, 0, 0);
        #pragma unroll
        for (int rt = 0; rt < 4; ++rt) {
            int node = rbase + rt * 16 + l16;
            if (node < nlim) {
                short4 s;
                s.x = f2bf(acc[rt][0]); s.y = f2bf(acc[rt][1]);
                s.z = f2bf(acc[rt][2]); s.w = f2bf(acc[rt][3]);
                *(short4*)(Y + (size_t)node * 128 + nt * 16 + quad * 4) = s;
            }
        }
    }
}

// ---------------- fused GATv2 aggregation — R6 STATIC SCHEDULE, PACKED MATH (R18) ----
// 4 dst/wave, 16 lanes/dst, launch_bounds (256,2).
// Closed levers: scheduling (R7 steal=convoy, R8 wave-steal=contention, R9
// snake=locality loss) and occupancy (R4/R11: (256,4) spills — kernel needs
// >128 VGPR, can't run 4 waves/SIMD).
// R18: hot-loop math moved from float4 structs to native f32x4 vectors with
// fused expressions -> v_pk_fma_f32 / v_pk_max_f32 (VOP3P, 2 f32/inst),
// targeting the dominant VALU cost directly.

template<bool RELU>
__global__ __launch_bounds__(256, 2) void agg2_k(
    const short* __restrict__ xl0, const short* __restrict__ xr0,
    const short* __restrict__ eas0, const int* __restrict__ csrsrc0,
    const float* __restrict__ We0, const float* __restrict__ att0,
    const float* __restrict__ bias0, const int4* __restrict__ jobs0,
    float* __restrict__ out0, short* __restrict__ outb0, int nd0, int nblk0,
    const short* __restrict__ xl1, const short* __restrict__ xr1,
    const short* __restrict__ eas1, const int* __restrict__ csrsrc1,
    const float* __restrict__ We1, const float* __restrict__ att1,
    const float* __restrict__ bias1, const int4* __restrict__ jobs1,
    float* __restrict__ out1, short* __restrict__ outb1, int nd1, int nblk1,
    int nblkB0) {

    int wave = threadIdx.x >> 6;
    int lane = threadIdx.x & 63;
    int g = lane >> 4;
    int sl = lane & 15;
    int c = sl * 8;

    // static partition: which segment does this block serve?
    const short* xl; const short* xrp; const short* eas; const int* csrsrc;
    const float* We; const float* att; const float* bias;
    const int4* jobs;
    float* out; short* outb; int ndst, nblk, blk, stride;
    if ((int)blockIdx.x < nblkB0) {
        xl = xl0; xrp = xr0; eas = eas0; csrsrc = csrsrc0; We = We0; att = att0; bias = bias0;
        jobs = jobs0; out = out0; outb = outb0; ndst = nd0; nblk = nblk0;
        blk = blockIdx.x; stride = nblkB0;
    } else {
        xl = xl1; xrp = xr1; eas = eas1; csrsrc = csrsrc1; We = We1; att = att1; bias = bias1;
        jobs = jobs1; out = out1; outb = outb1; ndst = nd1; nblk = nblk1;
        blk = blockIdx.x - nblkB0; stride = gridDim.x - nblkB0;
    }
    if (blk >= nblk) return;

    // per-segment invariants, pinned in VGPRs (loaded exactly once per block)
    f32x4 WeA[8], WeB[8];
    #pragma unroll
    for (int k = 0; k < 8; ++k) {
        WeA[k] = *(const f32x4*)(We + k * 128 + c);
        WeB[k] = *(const f32x4*)(We + k * 128 + c + 4);
    }
    f32x4 attA = *(const f32x4*)(att + c);
    f32x4 attB = *(const f32x4*)(att + c + 4);
    f32x4 bA = *(const f32x4*)(bias + c);
    f32x4 bB = *(const f32x4*)(bias + c + 4);
    #pragma unroll
    for (int k = 0; k < 8; ++k) {
        asm volatile("" : "+v"(WeA[k]));
        asm volatile("" : "+v"(WeB[k]));
    }
    asm volatile("" : "+v"(attA));
    asm volatile("" : "+v"(attB));

    auto load_job = [&](int b) -> int4 {
        int di = b * 16 + wave * 4 + g;
        bool h = di < ndst;
        int4 j = jobs[h ? (ndst - 1 - di) : 0];   // LPT: heaviest first
        if (!h) j.z = 0;
        j.w = h ? 1 : 0;
        return j;
    };

    // group-level pipeline: job + xr row for the first group
    int4 jb = load_job(blk);
    bf16x8 xrb = *(const bf16x8*)(xrp + (size_t)jb.x * 128 + c);

    for (; blk < nblk; blk += stride) {
        int nb = blk + stride;
        int4 jbN = (nb < nblk) ? load_job(nb) : make_int4(0, 0, 0, 0);

        int d = jb.x, e0 = jb.y, cnt = jb.z;
        bool has = jb.w != 0;
        f32x4 xrA = bfh2v4(xrb, 0), xrB = bfh2v4(xrb, 1);

        f32x4 accA = {0,0,0,0}, accB = {0,0,0,0};
        float den = 0.f, mrun = -INFINITY;
        int last = (cnt > 0) ? e0 + cnt - 1 : 0;

        int mc = cnt;
        mc = max(mc, __shfl_xor(mc, 16, 64));
        mc = max(mc, __shfl_xor(mc, 32, 64));
        int niter = (mc + 3) >> 2;

        auto lds_idx = [&](int ib, int* s) {
            #pragma unroll
            for (int j = 0; j < 4; ++j) {
                int cj = (ib + j < last) ? ib + j : last;
                s[j] = csrsrc[cj];
            }
        };
        auto lds_ea = [&](int ib, bf16x8* ea) {
            #pragma unroll
            for (int j = 0; j < 4; ++j) {
                int cj = (ib + j < last) ? ib + j : last;
                ea[j] = *(const bf16x8*)(eas + (size_t)cj * 8);
            }
        };
        auto lds_x = [&](const int* s, bf16x8* xb) {
            #pragma unroll
            for (int j = 0; j < 4; ++j)
                xb[j] = *(const bf16x8*)(xl + (size_t)s[j] * 128 + c);
        };

        int sA[4], sB[4];
        bf16x8 xbA[4], xbB[4], eaA[4], eaB[4];

        if (niter > 0) {
            int st[4];
            lds_idx(e0, st);
            lds_ea(e0, eaA);
            lds_x(st, xbA);
            lds_idx(e0 + 4, sA);
        }

        auto step = [&](int i, bf16x8 (&xbC)[4], bf16x8 (&eaC)[4], int (&sNx)[4],
                        bf16x8 (&xbN)[4], bf16x8 (&eaN)[4], int (&sN2)[4]) {
            lds_x(sNx, xbN);
            lds_ea(e0 + i + 4, eaN);
            lds_idx(e0 + i + 8, sN2);

            f32x4 x0A = bfh2v4(xbC[0], 0), x0B = bfh2v4(xbC[0], 1);
            f32x4 x1A = bfh2v4(xbC[1], 0), x1B = bfh2v4(xbC[1], 1);
            f32x4 x2A = bfh2v4(xbC[2], 0), x2B = bfh2v4(xbC[2], 1);
            f32x4 x3A = bfh2v4(xbC[3], 0), x3B = bfh2v4(xbC[3], 1);

            auto logit = [&](f32x4 xA, f32x4 xB, bf16x8 eab) -> float {
                f32x4 ea = bfh2v4(eab, 0), eb = bfh2v4(eab, 1);
                f32x4 mA = xA + xrA, mB = xB + xrB;
                mA += ea.x * WeA[0]; mB += ea.x * WeB[0];
                mA += ea.y * WeA[1]; mB += ea.y * WeB[1];
                mA += ea.z * WeA[2]; mB += ea.z * WeB[2];
                mA += ea.w * WeA[3]; mB += ea.w * WeB[3];
                mA += eb.x * WeA[4]; mB += eb.x * WeB[4];
                mA += eb.y * WeA[5]; mB += eb.y * WeB[5];
                mA += eb.z * WeA[6]; mB += eb.z * WeB[6];
                mA += eb.w * WeA[7]; mB += eb.w * WeB[7];
                return v4dot(v4leaky(mA), attA) + v4dot(v4leaky(mB), attB);
            };

            float t0 = logit(x0A, x0B, eaC[0]);
            float t1 = logit(x1A, x1B, eaC[1]);
            float t2 = logit(x2A, x2B, eaC[2]);
            float t3 = logit(x3A, x3B, eaC[3]);
            #pragma unroll
            for (int off = 8; off; off >>= 1) {
                t0 += __shfl_xor(t0, off, 64);
                t1 += __shfl_xor(t1, off, 64);
                t2 += __shfl_xor(t2, off, 64);
                t3 += __shfl_xor(t3, off, 64);
            }
            if (i + 1 >= cnt) t1 = -INFINITY;
            if (i + 2 >= cnt) t2 = -INFINITY;
            if (i + 3 >= cnt) t3 = -INFINITY;

            if (i < cnt) {
                float m4 = fmaxf(fmaxf(t0, t1), fmaxf(t2, t3));
                float nm = fmaxf(mrun, m4);
                float sc = __expf(mrun - nm);
                float p0 = __expf(t0 - nm);
                float p1 = __expf(t1 - nm);
                float p2 = __expf(t2 - nm);
                float p3 = __expf(t3 - nm);
                den = den * sc + p0 + p1 + p2 + p3;
                accA = sc * accA + p0 * x0A;
                accA += p1 * x1A;
                accA += p2 * x2A;
                accA += p3 * x3A;
                accB = sc * accB + p0 * x0B;
                accB += p1 * x1B;
                accB += p2 * x2B;
                accB += p3 * x3B;
                mrun = nm;
            }
        };

        int it = 0;
        for (; it + 1 < niter; it += 2) {
            step(it * 4,     xbA, eaA, sA, xbB, eaB, sB);
            step(it * 4 + 4, xbB, eaB, sB, xbA, eaA, sA);
        }
        if (it < niter)
            step(it * 4, xbA, eaA, sA, xbB, eaB, sB);

        float inv = 1.f / fmaxf(den, 1e-16f);
        f32x4 oA = accA * inv + bA;
        f32x4 oB = accB * inv + bB;
        if (RELU) {
            oA = v4max0(oA);
            oB = v4max0(oB);
        }
        float ss = v4dot(oA, oA) + v4dot(oB, oB);
        #pragma unroll
        for (int off = 8; off; off >>= 1) ss += __shfl_xor(ss, off, 64);
        float innv = 1.f / fmaxf(sqrtf(ss), 1e-12f);
        oA = oA * innv;
        oB = oB * innv;
        if (has) {
            if (out) {
                f32x4* op = (f32x4*)(out + (size_t)d * 128 + c);
                op[0] = oA;
                op[1] = oB;
            }
            if (outb) {
                bf16x8 pk;
                pk[0] = f2bf(oA.x); pk[1] = f2bf(oA.y); pk[2] = f2bf(oA.z); pk[3] = f2bf(oA.w);
                pk[4] = f2bf(oB.x); pk[5] = f2bf(oB.y); pk[6] = f2bf(oB.z); pk[7] = f2bf(oB.w);
                *(bf16x8*)(outb + (size_t)d * 128 + c) = pk;
            }
        }

        // prefetch next chunk's xr row (hides under next chunk's gather chain)
        bf16x8 xrbN = *(const bf16x8*)(xrp + (size_t)jbN.x * 128 + c);
        jb = jbN;
        xrb = xrbN;
    }
}

// ---------------- launch ----------------

extern "C" void kernel_launch(void* const* d_in, const int* in_sizes, int n_in,
                              void* d_out, int out_size, void* d_ws, size_t ws_size,
                              hipStream_t stream) {
    const float* x_artist = (const float*)d_in[0];
    const float* x_style  = (const float*)d_in[1];
    const int*   src_aa   = (const int*)d_in[2];
    const int*   dst_aa   = (const int*)d_in[3];
    const float* eattr_aa = (const float*)d_in[4];
    const int*   src_as   = (const int*)d_in[5];
    const int*   dst_as   = (const int*)d_in[6];
    const float* eattr_as = (const float*)d_in[7];
    const float* Wl0_aa = (const float*)d_in[8];
    const float* Wr0_aa = (const float*)d_in[9];
    const float* att0_aa = (const float*)d_in[10];
    const float* We0_aa = (const float*)d_in[11];
    const float* b0_aa = (const float*)d_in[12];
    const float* Wl0_as = (const float*)d_in[13];
    const float* Wr0_as = (const float*)d_in[14];
    const float* att0_as = (const float*)d_in[15];
    const float* We0_as = (const float*)d_in[16];
    const float* b0_as = (const float*)d_in[17];
    const float* Wl_aa = (const float*)d_in[18];
    const float* Wr_aa = (const float*)d_in[19];
    const float* att_aa = (const float*)d_in[20];
    const float* We_aa = (const float*)d_in[21];
    const float* b_aa = (const float*)d_in[22];
    const float* Wl_as = (const float*)d_in[23];
    const float* Wr_as = (const float*)d_in[24];
    const float* att_as = (const float*)d_in[25];
    const float* We_as = (const float*)d_in[26];
    const float* b_as = (const float*)d_in[27];

    float* out = (float*)d_out;

    // ws layout: bf16 regions, then int regions
    short* Xb    = (short*)d_ws;                       // [NAPAD][128]
    short* Xsb   = Xb + (size_t)NAPAD * 128;           // [NSPAD][128]
    short* Wt    = Xsb + (size_t)NSPAD * 128;          // [3][4][128][128]
    short* bufAb = Wt + 12 * 16384;                    // xl_aa
    short* bufDb = bufAb + (size_t)NA * 128;           // xl_as
    short* bufBb = bufDb + (size_t)NA * 128;           // xr_aa
    short* bufCb = bufBb + (size_t)NA * 128;           // xr_as
    short* easAA = bufCb + (size_t)NSPAD * 128;        // [E_AA][8]
    short* easAS = easAA + (size_t)E_AA * 8;           // [E_AS][8]
    int* ip = (int*)(easAS + (size_t)E_AS * 8);        // 16B-aligned
    // zeroed zone
    int* zbase  = ip;
    int* deg_aa = ip;            ip += NA;
    int* cur_aa = ip;            ip += NA;
    int* deg_as = ip;            ip += NS;
    int* cur_as = ip;            ip += NS;
    int* dh_aa  = ip;            ip += 256;
    int* dh_as  = ip;            ip += 256;
    int* dcur_aa = ip;           ip += 256;
    int* dcur_as = ip;           ip += 256;
    size_t zbytes = (size_t)(ip - zbase) * sizeof(int);
    // non-zeroed (jobs first: int4-aligned — zero zone stays 16B-multiple)
    int4* jobs_aa = (int4*)ip;   ip += 4 * NA;
    int4* jobs_as = (int4*)ip;   ip += 4 * NS;
    int* rs_aa  = ip;            ip += NA + 1;
    int* rs_as  = ip;            ip += NS + 1;
    int* csrsrc_aa = ip;         ip += E_AA;
    int* csrsrc_as = ip;         ip += E_AS;
    int* dbo_aa = ip;            ip += 256;
    int* dbo_as = ip;            ip += 256;
    int* bsum   = ip;            ip += 64;

    const int nbA_scan = (NA + SCAN_CH - 1) / SCAN_CH;
    const int nbS_scan = (NS + SCAN_CH - 1) / SCAN_CH;
    const int nbA_node = (NA + 255) / 256;
    const int nbS_node = (NS + 255) / 256;
    const int gE = (E_AA + 255) / 256;                   // 1954
    const int gCvt = (NAPAD * 32 + NSPAD * 32 + 255) / 256;
    const int gWtr = 12 * 64;

    // ---- preprocessing ----
    hipMemsetAsync(zbase, 0, zbytes, stream);
    prep1_k<<<gE + gCvt + gWtr, 256, 0, stream>>>(
        dst_aa, dst_as, deg_aa, deg_as,
        x_artist, x_style, Xb, Xsb,
        Wl0_aa, Wr0_aa, Wl0_as, Wr0_as, Wl_aa, Wr_aa, Wl_as, Wr_as, Wt,
        gE, gCvt);
    scanA_k<<<nbA_scan + nbS_scan, 256, 0, stream>>>(deg_aa, NA, deg_as, NS, nbA_scan, bsum);
    scanB_k<<<1, 64, 0, stream>>>(bsum, nbA_scan, nbS_scan);
    scanC_k<<<nbA_scan + nbS_scan, 256, 0, stream>>>(deg_aa, NA, deg_as, NS, nbA_scan,
                                                     bsum, rs_aa, rs_as);
    scatter2_k<<<gE, 256, 0, stream>>>(dst_aa, src_aa, eattr_aa,
                                       dst_as, src_as, eattr_as,
                                       rs_aa, rs_as, cur_aa, cur_as,
                                       csrsrc_aa, csrsrc_as, easAA, easAS);
    deghist2_k<<<nbA_node + nbS_node, 256, 0, stream>>>(rs_aa, NA, rs_as, NS, nbA_node,
                                                        dh_aa, dh_as);
    binscan2_k<<<1, 128, 0, stream>>>(dh_aa, dh_as, dbo_aa, dbo_as);
    degscatter2_k<<<nbA_node + nbS_node, 256, 0, stream>>>(rs_aa, NA, rs_as, NS, nbA_node,
                                                           dbo_aa, dbo_as, dcur_aa, dcur_as,
                                                           jobs_aa, jobs_as);

    const int gM = NAPAD / 256;       // 196
    const int gS4 = NSPAD / 256;      // 20
    const int aggA = (NA + 15) / 16;  // 3125 dst-chunks
    const int aggS = (NS + 15) / 16;  // 313

    for (int layer = 0; layer < 3; ++layer) {
        int j = layer - 1;
        const float *patt_aa, *pWe_aa, *pb_aa, *patt_as, *pWe_as, *pb_as;
        if (layer == 0) {
            patt_aa = att0_aa; pWe_aa = We0_aa; pb_aa = b0_aa;
            patt_as = att0_as; pWe_as = We0_as; pb_as = b0_as;
        } else {
            patt_aa = att_aa + (size_t)j * CDIM;
            pWe_aa = We_aa + (size_t)j * ED * CDIM;
            pb_aa = b_aa + (size_t)j * CDIM;
            patt_as = att_as + (size_t)j * CDIM;
            pWe_as = We_as + (size_t)j * ED * CDIM;
            pb_as = b_as + (size_t)j * CDIM;
        }
        const short* pWt = Wt + (size_t)layer * 4 * 16384;
        float* hA_out = (layer == 2) ? out : nullptr;
        float* hS_out = (layer == 2) ? out + (size_t)NA * CDIM : nullptr;
        short* hA_outb = (layer == 2) ? nullptr : Xb;
        short* hS_outb = (layer == 2) ? nullptr : Xsb;

        gemm4_k<<<3 * gM + gS4, 256, 0, stream>>>(Xb, Xsb, pWt, bufAb, bufBb, bufDb, bufCb, gM);

        if (layer < 2)
            agg2_k<true><<<AGG_BLOCKS, 256, 0, stream>>>(
                bufAb, bufBb, easAA, csrsrc_aa, pWe_aa, patt_aa, pb_aa,
                jobs_aa, hA_out, hA_outb, NA, aggA,
                bufDb, bufCb, easAS, csrsrc_as, pWe_as, patt_as, pb_as,
                jobs_as, hS_out, hS_outb, NS, aggS, AGG_BLK_AA);
        else
            agg2_k<false><<<AGG_BLOCKS, 256, 0, stream>>>(
                bufAb, bufBb, easAA, csrsrc_aa, pWe_aa, patt_aa, pb_aa,
                jobs_aa, hA_out, hA_outb, NA, aggA,
                bufDb, bufCb, easAS, csrsrc_as, pWe_as, patt_as, pb_as,
                jobs_as, hS_out, hS_outb, NS, aggS, AGG_BLK_AA);
    }
}